// Round 1
// baseline (445.882 us; speedup 1.0000x reference)
//
#include <hip/hip_runtime.h>

// Problem constants (from reference)
#define H_DIM 2048
#define E_DIM 8
#define T_DIM 2048
#define F_DIM 4096              // INTER*2
#define ROWS (E_DIM * H_DIM)    // 16384 (e,h) rows of W, each F_DIM floats
#define ROWSUM_BLOCKS (ROWS / 4)   // 4096 blocks, one 64-lane wave per row
#define HBLOCKS (H_DIM / 256)      // 8
#define TCHUNK 128
#define TCHUNKS (T_DIM / TCHUNK)   // 16
#define MS_BLOCKS (HBLOCKS * TCHUNKS)  // 128

// ws layout: [0, ROWS) = B row sums; [ROWS, ROWS + TCHUNKS*ROWS) = A partials

__global__ __launch_bounds__(256) void fused_compute(
    const float* __restrict__ hidden,   // [T, H]
    const float* __restrict__ W,        // [E, H, F]
    const float* __restrict__ mask,     // [E, T]
    float* __restrict__ ws) {
  float* Bsum = ws;                // ROWS floats
  float* Ap   = ws + ROWS;         // TCHUNKS * ROWS floats

  int bid = blockIdx.x;
  if (bid < ROWSUM_BLOCKS) {
    // --- B[e,h] = sum_f W[e,h,f].  One wave per (e,h) row. ---
    int wave = (bid << 2) | (threadIdx.x >> 6);
    int lane = threadIdx.x & 63;
    const float4* row = (const float4*)(W + (size_t)wave * F_DIM);
    float s = 0.f;
    // F/4 = 1024 float4 per row; 64 lanes -> 16 iterations, 16B/lane coalesced
    #pragma unroll
    for (int i = 0; i < 16; ++i) {
      float4 v = row[lane + (i << 6)];
      s += (v.x + v.y) + (v.z + v.w);
    }
    #pragma unroll
    for (int off = 32; off > 0; off >>= 1)
      s += __shfl_down(s, off, 64);
    if (lane == 0) Bsum[wave] = s;
  } else {
    // --- A[e,h] partials: A[e,h] = sum_t mask[e,t]*hidden[t,h] ---
    int b  = bid - ROWSUM_BLOCKS;
    int hb = b & (HBLOCKS - 1);
    int tc = b >> 3;                 // 16 t-chunks
    int h  = (hb << 8) + threadIdx.x;
    int t0 = tc * TCHUNK;
    float acc[E_DIM];
    #pragma unroll
    for (int e = 0; e < E_DIM; ++e) acc[e] = 0.f;
    #pragma unroll 4
    for (int t = t0; t < t0 + TCHUNK; ++t) {
      float hv = hidden[(size_t)t * H_DIM + h];  // coalesced across block
      #pragma unroll
      for (int e = 0; e < E_DIM; ++e)
        acc[e] += hv * mask[e * T_DIM + t];      // wave-uniform broadcast
    }
    #pragma unroll
    for (int e = 0; e < E_DIM; ++e)
      Ap[(size_t)tc * ROWS + e * H_DIM + h] = acc[e];
  }
}

__global__ __launch_bounds__(256) void dot_kernel(const float* __restrict__ ws,
                                                  float* __restrict__ out) {
  const float* Bsum = ws;
  const float* Ap   = ws + ROWS;
  float s = 0.f;
  for (int i = threadIdx.x; i < ROWS; i += 256) {
    float a = 0.f;
    #pragma unroll
    for (int c = 0; c < TCHUNKS; ++c) a += Ap[(size_t)c * ROWS + i];
    s += a * Bsum[i];
  }
  #pragma unroll
  for (int off = 32; off > 0; off >>= 1)
    s += __shfl_down(s, off, 64);
  __shared__ float red[4];
  int wave = threadIdx.x >> 6;
  int lane = threadIdx.x & 63;
  if (lane == 0) red[wave] = s;
  __syncthreads();
  if (threadIdx.x == 0) out[0] = (red[0] + red[1]) + (red[2] + red[3]);
}

extern "C" void kernel_launch(void* const* d_in, const int* in_sizes, int n_in,
                              void* d_out, int out_size, void* d_ws, size_t ws_size,
                              hipStream_t stream) {
  const float* hidden = (const float*)d_in[0];  // [1,1,T,H] fp32
  const float* W      = (const float*)d_in[1];  // [1,E,H,2*INTER] fp32
  const float* mask   = (const float*)d_in[2];  // [1,E,T,1] fp32
  float* out = (float*)d_out;                   // scalar
  float* ws  = (float*)d_ws;                    // needs (1+TCHUNKS)*ROWS*4 = ~1.07 MB

  fused_compute<<<ROWSUM_BLOCKS + MS_BLOCKS, 256, 0, stream>>>(hidden, W, mask, ws);
  dot_kernel<<<1, 256, 0, stream>>>(ws, out);
}

// Round 2
// 400.396 us; speedup vs baseline: 1.1136x; 1.1136x over previous
//
#include <hip/hip_runtime.h>

// Problem constants (from reference)
#define H_DIM 2048
#define E_DIM 8
#define T_DIM 2048
#define F_DIM 4096              // INTER*2
#define ROWS (E_DIM * H_DIM)    // 16384 (e,h) rows of W, each F_DIM floats
#define ROWSUM_BLOCKS (ROWS / 4)   // 4096 blocks, one 64-lane wave per row
#define HBLOCKS (H_DIM / 256)      // 8
#define TCHUNK 512
#define TCHUNKS (T_DIM / TCHUNK)   // 4
#define MS_BLOCKS (HBLOCKS * TCHUNKS)  // 32  (scheduled FIRST to overlap)

typedef float f32x4 __attribute__((ext_vector_type(4)));

// ws layout: [0, ROWS) = B row sums; [ROWS, ROWS + TCHUNKS*ROWS) = A partials
// total = 5*ROWS*4 = 320 KB << ws_size

__global__ __launch_bounds__(256) void fused_compute(
    const float* __restrict__ hidden,   // [T, H]
    const float* __restrict__ W,        // [E, H, F]
    const float* __restrict__ mask,     // [E, T]
    float* __restrict__ ws) {
  float* Bsum = ws;                // ROWS floats
  float* Ap   = ws + ROWS;         // TCHUNKS * ROWS floats

  int bid = blockIdx.x;
  if (bid >= MS_BLOCKS) {
    // --- B[e,h] = sum_f W[e,h,f].  One wave per (e,h) row, streamed NT. ---
    int wave = ((bid - MS_BLOCKS) << 2) | (threadIdx.x >> 6);
    int lane = threadIdx.x & 63;
    const f32x4* row = (const f32x4*)(W + (size_t)wave * F_DIM);
    float s = 0.f;
    // F/4 = 1024 float4 per row; 64 lanes -> 16 iterations, 16B/lane coalesced
    #pragma unroll
    for (int i = 0; i < 16; ++i) {
      f32x4 v = __builtin_nontemporal_load(row + lane + (i << 6));
      s += (v.x + v.y) + (v.z + v.w);
    }
    #pragma unroll
    for (int off = 32; off > 0; off >>= 1)
      s += __shfl_down(s, off, 64);
    if (lane == 0) Bsum[wave] = s;
  } else {
    // --- A[e,h] partials: A[e,h] = sum_t mask[e,t]*hidden[t,h] ---
    int hb = bid & (HBLOCKS - 1);
    int tc = bid >> 3;                 // 4 t-chunks of 512
    int h  = (hb << 8) + threadIdx.x;
    int t0 = tc * TCHUNK;

    // Stage this chunk's masks in LDS: [E][TCHUNK] = 8*512 floats = 16 KB
    __shared__ float m_lds[E_DIM][TCHUNK];
    #pragma unroll
    for (int i = 0; i < (E_DIM * TCHUNK) / 256; ++i) {
      int idx = i * 256 + threadIdx.x;
      int e = idx / TCHUNK, tt = idx % TCHUNK;
      m_lds[e][tt] = mask[e * T_DIM + t0 + tt];
    }
    __syncthreads();

    float acc[E_DIM];
    #pragma unroll
    for (int e = 0; e < E_DIM; ++e) acc[e] = 0.f;
    #pragma unroll 4
    for (int t = 0; t < TCHUNK; ++t) {
      float hv = hidden[(size_t)(t0 + t) * H_DIM + h];  // coalesced across block
      #pragma unroll
      for (int e = 0; e < E_DIM; ++e)
        acc[e] += hv * m_lds[e][t];      // same-address broadcast, conflict-free
    }
    #pragma unroll
    for (int e = 0; e < E_DIM; ++e)
      Ap[(size_t)tc * ROWS + e * H_DIM + h] = acc[e];
  }
}

__global__ __launch_bounds__(1024) void dot_kernel(const float* __restrict__ ws,
                                                   float* __restrict__ out) {
  const float* Bsum = ws;
  const float* Ap   = ws + ROWS;
  float s = 0.f;
  #pragma unroll
  for (int i0 = 0; i0 < ROWS; i0 += 1024) {
    int i = i0 + threadIdx.x;
    float a = (Ap[i] + Ap[ROWS + i]) + (Ap[2 * ROWS + i] + Ap[3 * ROWS + i]);
    s += a * Bsum[i];
  }
  #pragma unroll
  for (int off = 32; off > 0; off >>= 1)
    s += __shfl_down(s, off, 64);
  __shared__ float red[16];
  int wave = threadIdx.x >> 6;
  int lane = threadIdx.x & 63;
  if (lane == 0) red[wave] = s;
  __syncthreads();
  if (threadIdx.x == 0) {
    float r = 0.f;
    #pragma unroll
    for (int w = 0; w < 16; ++w) r += red[w];
    out[0] = r;
  }
}

extern "C" void kernel_launch(void* const* d_in, const int* in_sizes, int n_in,
                              void* d_out, int out_size, void* d_ws, size_t ws_size,
                              hipStream_t stream) {
  const float* hidden = (const float*)d_in[0];  // [1,1,T,H] fp32
  const float* W      = (const float*)d_in[1];  // [1,E,H,2*INTER] fp32
  const float* mask   = (const float*)d_in[2];  // [1,E,T,1] fp32
  float* out = (float*)d_out;                   // scalar
  float* ws  = (float*)d_ws;

  fused_compute<<<ROWSUM_BLOCKS + MS_BLOCKS, 256, 0, stream>>>(hidden, W, mask, ws);
  dot_kernel<<<1, 1024, 0, stream>>>(ws, out);
}